// Round 5
// baseline (73.693 us; speedup 1.0000x reference)
//
#include <hip/hip_runtime.h>

#define N_POINTS 16384
#define D_FEAT   256
#define K_NB     8
#define G        12
#define NCELL    (G * G * G)      // 1728
#define BIN_T    1024

__device__ __forceinline__ int clampi(int v, int lo, int hi) {
    return min(max(v, lo), hi);
}

// ---------- bin_kernel: hist + scan + scatter, one block, all in LDS --------
__global__ __launch_bounds__(BIN_T) void bin_kernel(const float* __restrict__ coords,
                                                    int* __restrict__ cell_start,
                                                    float4* __restrict__ sorted) {
    __shared__ int h[NCELL];               // 6.75 KB
    __shared__ int cur[NCELL];             // 6.75 KB
    __shared__ unsigned short cid[N_POINTS]; // 32 KB
    __shared__ int wt[16];
    const int tid = threadIdx.x;

    for (int c = tid; c < NCELL; c += BIN_T) h[c] = 0;
    __syncthreads();

    // histogram (LDS atomics) + cache cell ids
    for (int i = tid; i < N_POINTS; i += BIN_T) {
        const float x = coords[3 * i], y = coords[3 * i + 1], z = coords[3 * i + 2];
        const int cx = clampi((int)(x * (float)G), 0, G - 1);
        const int cy = clampi((int)(y * (float)G), 0, G - 1);
        const int cz = clampi((int)(z * (float)G), 0, G - 1);
        const int c = (cz * G + cy) * G + cx;
        cid[i] = (unsigned short)c;
        atomicAdd(&h[c], 1);
    }
    __syncthreads();

    // exclusive scan: 2 cells per thread, wave scan + wave-total combine
    const int lane = tid & 63, wave = tid >> 6;
    const int t2 = tid * 2;
    int a = (t2 < NCELL) ? h[t2] : 0;
    int b = (t2 + 1 < NCELL) ? h[t2 + 1] : 0;
    int v = a + b;
    #pragma unroll
    for (int off = 1; off < 64; off <<= 1) {
        int o = __shfl_up(v, off, 64);
        if (lane >= off) v += o;
    }
    if (lane == 63) wt[wave] = v;
    __syncthreads();
    int woff = 0;
    #pragma unroll
    for (int w = 0; w < 16; ++w) woff += (w < wave) ? wt[w] : 0;
    const int ex = woff + v - a - b;
    if (t2 < NCELL)     { cur[t2]     = ex;     cell_start[t2]     = ex; }
    if (t2 + 1 < NCELL) { cur[t2 + 1] = ex + a; cell_start[t2 + 1] = ex + a; }
    if (tid == 0) cell_start[NCELL] = N_POINTS;
    __syncthreads();

    // scatter (coords re-read is L2-hot)
    for (int i = tid; i < N_POINTS; i += BIN_T) {
        const int c = cid[i];
        const int slot = atomicAdd(&cur[c], 1);
        sorted[slot] = make_float4(coords[3 * i], coords[3 * i + 1], coords[3 * i + 2],
                                   __int_as_float(i));
    }
}

// sorted top-8 insert, fully static indexing
#define INSERT(d2v, jv)                                                    \
    if ((d2v) < bd[7]) {                                                   \
        bd[7] = (d2v); bi[7] = (jv);                                       \
        _Pragma("unroll")                                                  \
        for (int _k = 7; _k > 0; --_k) {                                   \
            if (bd[_k] < bd[_k - 1]) {                                     \
                float _td = bd[_k]; bd[_k] = bd[_k - 1]; bd[_k - 1] = _td; \
                int   _ti = bi[_k]; bi[_k] = bi[_k - 1]; bi[_k - 1] = _ti; \
            }                                                              \
        }                                                                  \
    }

// ---------- knn + cosine (norms fused): one wave per query ------------------
__global__ __launch_bounds__(256) void knn_cos_kernel(const float4* __restrict__ sorted,
                                                      const int* __restrict__ cell_start,
                                                      const float* __restrict__ feat,
                                                      float* __restrict__ partial) {
    const int tid  = threadIdx.x;
    const int lane = tid & 63;
    const int wave = tid >> 6;
    const int q    = blockIdx.x * 4 + wave;       // sorted position

    const float4 qp = sorted[q];
    const float xi = qp.x, yi = qp.y, zi = qp.z;
    const int qorig = __float_as_int(qp.w);
    const int cx = clampi((int)(xi * (float)G), 0, G - 1);
    const int cy = clampi((int)(yi * (float)G), 0, G - 1);
    const int cz = clampi((int)(zi * (float)G), 0, G - 1);
    const int x0 = max(cx - 1, 0), x1 = min(cx + 1, G - 1);

    // lanes 0..8 fetch the 9 segment bounds in parallel
    int sv = 0, ev = 0;
    {
        const int dz = lane / 3 - 1, dy = lane % 3 - 1;   // meaningful for lane<9
        const int z = cz + dz, y = cy + dy;
        const bool valid = (lane < 9) && z >= 0 && z < G && y >= 0 && y < G;
        if (valid) {
            const int rowb = (z * G + y) * G;
            sv = cell_start[rowb + x0];
            ev = cell_start[rowb + x1 + 1];
        }
    }

    float bd[8];
    int   bi[8];
    #pragma unroll
    for (int k = 0; k < 8; ++k) { bd[k] = 3.4e38f; bi[k] = -1; }

    #pragma unroll
    for (int r = 0; r < 9; ++r) {
        const int s = __shfl(sv, r, 64);
        const int e = __shfl(ev, r, 64);
        for (int bpos = s; bpos < e; bpos += 64) {
            const int idx = bpos + lane;
            if (idx < e) {
                const float4 p = sorted[idx];
                const float dx = p.x - xi, dy2 = p.y - yi, dz2 = p.z - zi;
                const float d2 = fmaf(dx, dx, fmaf(dy2, dy2, dz2 * dz2));
                const int j = __float_as_int(p.w);
                if (j != qorig) INSERT(d2, j);
            }
        }
    }

    // ---- wave merge: 8 rounds of u64 min over (d2 bits << 32 | idx) ----
    int nb[8];
    #pragma unroll
    for (int r = 0; r < K_NB; ++r) {
        unsigned long long my =
            ((unsigned long long)__float_as_uint(bd[0]) << 32) | (unsigned int)bi[0];
        unsigned long long w = my;
        #pragma unroll
        for (int off = 32; off > 0; off >>= 1) {
            unsigned long long o = __shfl_xor(w, off, 64);
            w = (o < w) ? o : w;
        }
        if (my == w) {                            // unique winner pops its head
            #pragma unroll
            for (int k = 0; k < 7; ++k) { bd[k] = bd[k + 1]; bi[k] = bi[k + 1]; }
            bd[7] = 3.4e38f; bi[7] = -1;
        }
        nb[r] = (int)(w & 0xFFFFFFFFu);
    }

    // ---- cosine with on-the-fly norms ----
    const float4* fq = reinterpret_cast<const float4*>(feat + (size_t)qorig * D_FEAT);
    const float4 aq = fq[lane];
    float sd[8], sn[8];
    #pragma unroll
    for (int r = 0; r < K_NB; ++r) {
        const int j = (nb[r] < 0) ? qorig : nb[r];
        const float4* fn = reinterpret_cast<const float4*>(feat + (size_t)j * D_FEAT);
        const float4 b = fn[lane];
        sd[r] = fmaf(aq.x, b.x, fmaf(aq.y, b.y, fmaf(aq.z, b.z, aq.w * b.w)));
        sn[r] = fmaf(b.x, b.x, fmaf(b.y, b.y, fmaf(b.z, b.z, b.w * b.w)));
    }
    float nq = fmaf(aq.x, aq.x, fmaf(aq.y, aq.y, fmaf(aq.z, aq.z, aq.w * aq.w)));
    #pragma unroll
    for (int off = 32; off > 0; off >>= 1) {
        nq += __shfl_xor(nq, off, 64);
        #pragma unroll
        for (int r = 0; r < K_NB; ++r) {
            sd[r] += __shfl_xor(sd[r], off, 64);
            sn[r] += __shfl_xor(sn[r], off, 64);
        }
    }
    const float rq = 1.0f / fmaxf(sqrtf(nq), 1e-12f);
    float acc = 0.0f;
    #pragma unroll
    for (int r = 0; r < K_NB; ++r)
        acc += 1.0f - sd[r] * rq / fmaxf(sqrtf(sn[r]), 1e-12f);

    __shared__ float wacc[4];
    if (lane == 0) wacc[wave] = acc;
    __syncthreads();
    if (tid == 0)
        partial[blockIdx.x] = wacc[0] + wacc[1] + wacc[2] + wacc[3];
}

// ---------- final reduction (4096 partials, fixed order) --------------------
__global__ __launch_bounds__(256) void reduce_kernel(const float* __restrict__ partial,
                                                     float* __restrict__ out) {
    const int tid  = threadIdx.x;
    const int lane = tid & 63;
    const int wave = tid >> 6;
    float s = 0.0f;
    for (int j = tid; j < N_POINTS / 4; j += 256) s += partial[j];
    #pragma unroll
    for (int off = 32; off > 0; off >>= 1) s += __shfl_xor(s, off, 64);
    __shared__ float sm[4];
    if (lane == 0) sm[wave] = s;
    __syncthreads();
    if (tid == 0)
        out[0] = 0.02f * (sm[0] + sm[1] + sm[2] + sm[3]) / (float)(N_POINTS * K_NB);
}

// ---------- launch ----------------------------------------------------------
extern "C" void kernel_launch(void* const* d_in, const int* in_sizes, int n_in,
                              void* d_out, int out_size, void* d_ws, size_t ws_size,
                              hipStream_t stream) {
    const float* feat   = (const float*)d_in[0];   // (16384, 256) f32
    const float* coords = (const float*)d_in[1];   // (16384, 3)  f32
    float* out = (float*)d_out;

    char* ws = (char*)d_ws;
    float4* sorted     = (float4*)ws;                         // 262144 B
    int*    cell_start = (int*)(ws + 262144);                 // (NCELL+1)*4 B
    float*  partial    = (float*)(ws + 262144 + 8192);        // 16384 B

    bin_kernel<<<1, BIN_T, 0, stream>>>(coords, cell_start, sorted);
    knn_cos_kernel<<<N_POINTS / 4, 256, 0, stream>>>(sorted, cell_start, feat, partial);
    reduce_kernel<<<1, 256, 0, stream>>>(partial, out);
}

// Round 6
// 55.920 us; speedup vs baseline: 1.3178x; 1.3178x over previous
//
#include <hip/hip_runtime.h>

#define N_POINTS 16384
#define D_FEAT   256
#define K_NB     8
#define G        12
#define NCELL    (G * G * G)      // 1728
#define PB_T     1024

__device__ __forceinline__ int clampi(int v, int lo, int hi) {
    return min(max(v, lo), hi);
}

// ---------- prep_bin: block 0 = hist+scan+scatter; blocks 1.. = rnorm -------
__global__ __launch_bounds__(PB_T) void prep_bin_kernel(const float* __restrict__ coords,
                                                        const float* __restrict__ feat,
                                                        int* __restrict__ cell_start,
                                                        float4* __restrict__ sorted,
                                                        float* __restrict__ rnorm) {
    __shared__ int h[NCELL];                 // 6.75 KB
    __shared__ int cur[NCELL];               // 6.75 KB
    __shared__ unsigned short cid[N_POINTS]; // 32 KB
    __shared__ int wt[16];
    const int tid  = threadIdx.x;
    const int lane = tid & 63;
    const int wave = tid >> 6;

    if (blockIdx.x == 0) {
        // ---- binning on one block (serial part, masks the rnorm blocks) ----
        for (int c = tid; c < NCELL; c += PB_T) h[c] = 0;
        __syncthreads();

        for (int i = tid; i < N_POINTS; i += PB_T) {
            const float x = coords[3 * i], y = coords[3 * i + 1], z = coords[3 * i + 2];
            const int cx = clampi((int)(x * (float)G), 0, G - 1);
            const int cy = clampi((int)(y * (float)G), 0, G - 1);
            const int cz = clampi((int)(z * (float)G), 0, G - 1);
            const int c = (cz * G + cy) * G + cx;
            cid[i] = (unsigned short)c;
            atomicAdd(&h[c], 1);
        }
        __syncthreads();

        // exclusive scan: 2 cells per thread
        const int t2 = tid * 2;
        int a = (t2 < NCELL) ? h[t2] : 0;
        int b = (t2 + 1 < NCELL) ? h[t2 + 1] : 0;
        int v = a + b;
        #pragma unroll
        for (int off = 1; off < 64; off <<= 1) {
            int o = __shfl_up(v, off, 64);
            if (lane >= off) v += o;
        }
        if (lane == 63) wt[wave] = v;
        __syncthreads();
        int woff = 0;
        #pragma unroll
        for (int w = 0; w < 16; ++w) woff += (w < wave) ? wt[w] : 0;
        const int ex = woff + v - a - b;
        if (t2 < NCELL)     { cur[t2]     = ex;     cell_start[t2]     = ex; }
        if (t2 + 1 < NCELL) { cur[t2 + 1] = ex + a; cell_start[t2 + 1] = ex + a; }
        if (tid == 0) cell_start[NCELL] = N_POINTS;
        __syncthreads();

        for (int i = tid; i < N_POINTS; i += PB_T) {
            const int c = cid[i];
            const int slot = atomicAdd(&cur[c], 1);
            sorted[slot] = make_float4(coords[3 * i], coords[3 * i + 1],
                                       coords[3 * i + 2], __int_as_float(i));
        }
    } else {
        // ---- rnorm: 16 rows per block, one row per wave ----
        const int row = (blockIdx.x - 1) * 16 + wave;
        const float4* f4 = reinterpret_cast<const float4*>(feat + (size_t)row * D_FEAT);
        float4 u = f4[lane];
        float s = u.x * u.x + u.y * u.y + u.z * u.z + u.w * u.w;
        #pragma unroll
        for (int off = 32; off > 0; off >>= 1) s += __shfl_xor(s, off, 64);
        if (lane == 0) rnorm[row] = 1.0f / fmaxf(sqrtf(s), 1e-12f);
    }
}

// ---------- knn + cosine: one wave per query --------------------------------
__global__ __launch_bounds__(256) void knn_cos_kernel(const float4* __restrict__ sorted,
                                                      const int* __restrict__ cell_start,
                                                      const float* __restrict__ feat,
                                                      const float* __restrict__ rnorm,
                                                      float* __restrict__ partial) {
    const int tid  = threadIdx.x;
    const int lane = tid & 63;
    const int wave = tid >> 6;
    const int q    = blockIdx.x * 4 + wave;       // sorted position

    const float4 qp = sorted[q];
    const float xi = qp.x, yi = qp.y, zi = qp.z;
    const int qorig = __float_as_int(qp.w);
    const int cx = clampi((int)(xi * (float)G), 0, G - 1);
    const int cy = clampi((int)(yi * (float)G), 0, G - 1);
    const int cz = clampi((int)(zi * (float)G), 0, G - 1);
    const int x0 = max(cx - 1, 0), x1 = min(cx + 1, G - 1);

    // lanes 0..8 fetch the 9 segment bounds in parallel
    int sv = 0, ev = 0;
    {
        const int dz = lane / 3 - 1, dy = lane % 3 - 1;   // meaningful for lane<9
        const int z = cz + dz, y = cy + dy;
        const bool valid = (lane < 9) && z >= 0 && z < G && y >= 0 && y < G;
        if (valid) {
            const int rowb = (z * G + y) * G;
            sv = cell_start[rowb + x0];
            ev = cell_start[rowb + x1 + 1];
        }
    }

    // ---- branchless per-lane top-2 over ~4 candidates ----
    const unsigned long long INF = 0xFFFFFFFFFFFFFFFFull;
    unsigned long long k0 = INF, k1 = INF;

    #pragma unroll
    for (int r = 0; r < 9; ++r) {
        const int s = __shfl(sv, r, 64);
        const int e = __shfl(ev, r, 64);
        for (int bpos = s; bpos < e; bpos += 64) {
            const int idx = bpos + lane;
            if (idx < e) {
                const float4 p = sorted[idx];
                const float dx = p.x - xi, dyv = p.y - yi, dzv = p.z - zi;
                const float d2 = fmaf(dx, dx, fmaf(dyv, dyv, dzv * dzv));
                const int j = __float_as_int(p.w);
                unsigned long long key =
                    ((unsigned long long)__float_as_uint(d2) << 32) | (unsigned int)j;
                key = (j == qorig) ? INF : key;
                const unsigned long long lo = (key < k0) ? key : k0;
                const unsigned long long hi = (key < k0) ? k0 : key;
                k0 = lo;
                k1 = (hi < k1) ? hi : k1;
            }
        }
    }

    // ---- merge: 8 rounds of wave-min over per-lane heads ----
    int nb[8];
    #pragma unroll
    for (int r = 0; r < K_NB; ++r) {
        unsigned long long m = k0;
        #pragma unroll
        for (int off = 32; off > 0; off >>= 1) {
            unsigned long long o = __shfl_xor(m, off, 64);
            m = (o < m) ? o : m;
        }
        const bool won = (k0 == m);
        k0 = won ? k1 : k0;
        k1 = won ? INF : k1;
        nb[r] = (int)(m & 0xFFFFFFFFu);
    }

    // ---- cosine: precomputed rnorm, single-value linear reduce ----
    const float4* fq = reinterpret_cast<const float4*>(feat + (size_t)qorig * D_FEAT);
    const float4 aq = fq[lane];
    const float rq = rnorm[qorig];
    float racc = 0.0f;
    #pragma unroll
    for (int r = 0; r < K_NB; ++r) {
        const int j = (nb[r] < 0) ? qorig : nb[r];
        const float4* fn = reinterpret_cast<const float4*>(feat + (size_t)j * D_FEAT);
        const float4 b = fn[lane];
        const float s = fmaf(aq.x, b.x, fmaf(aq.y, b.y, fmaf(aq.z, b.z, aq.w * b.w)));
        racc = fmaf(s, rq * rnorm[j], racc);
    }
    #pragma unroll
    for (int off = 32; off > 0; off >>= 1) racc += __shfl_xor(racc, off, 64);
    const float wval = (float)K_NB - racc;        // sum of (1 - cos)

    __shared__ float wacc[4];
    if (lane == 0) wacc[wave] = wval;
    __syncthreads();
    if (tid == 0)
        partial[blockIdx.x] = wacc[0] + wacc[1] + wacc[2] + wacc[3];
}

// ---------- final reduction (4096 partials, fixed order) --------------------
__global__ __launch_bounds__(256) void reduce_kernel(const float* __restrict__ partial,
                                                     float* __restrict__ out) {
    const int tid  = threadIdx.x;
    const int lane = tid & 63;
    const int wave = tid >> 6;
    float s = 0.0f;
    for (int j = tid; j < N_POINTS / 4; j += 256) s += partial[j];
    #pragma unroll
    for (int off = 32; off > 0; off >>= 1) s += __shfl_xor(s, off, 64);
    __shared__ float sm[4];
    if (lane == 0) sm[wave] = s;
    __syncthreads();
    if (tid == 0)
        out[0] = 0.02f * (sm[0] + sm[1] + sm[2] + sm[3]) / (float)(N_POINTS * K_NB);
}

// ---------- launch ----------------------------------------------------------
extern "C" void kernel_launch(void* const* d_in, const int* in_sizes, int n_in,
                              void* d_out, int out_size, void* d_ws, size_t ws_size,
                              hipStream_t stream) {
    const float* feat   = (const float*)d_in[0];   // (16384, 256) f32
    const float* coords = (const float*)d_in[1];   // (16384, 3)  f32
    float* out = (float*)d_out;

    char* ws = (char*)d_ws;
    float4* sorted     = (float4*)ws;                         // 262144 B
    int*    cell_start = (int*)(ws + 262144);                 // (NCELL+1)*4 B
    float*  rnorm      = (float*)(ws + 262144 + 8192);        // 65536 B
    float*  partial    = (float*)(ws + 262144 + 8192 + 65536);// 16384 B

    prep_bin_kernel<<<1 + N_POINTS / 16, PB_T, 0, stream>>>(coords, feat,
                                                            cell_start, sorted, rnorm);
    knn_cos_kernel<<<N_POINTS / 4, 256, 0, stream>>>(sorted, cell_start, feat,
                                                     rnorm, partial);
    reduce_kernel<<<1, 256, 0, stream>>>(partial, out);
}